// Round 8
// baseline (193.948 us; speedup 1.0000x reference)
//
#include <hip/hip_runtime.h>

// Problem constants
#define N_TOK 8192
#define N_EXP 8
#define DIM   2048
#define HID   2048

typedef __attribute__((ext_vector_type(8))) short short8;
typedef __attribute__((ext_vector_type(4))) float f32x4;
typedef __attribute__((ext_vector_type(4))) unsigned short ushort4v;

__device__ inline unsigned short f2bf(float f) {
  unsigned int u = __builtin_bit_cast(unsigned int, f);
  unsigned int r = u + 0x7FFFu + ((u >> 16) & 1u);   // round-to-nearest-even
  return (unsigned short)(r >> 16);
}

// ---------------------------------------------------------------------------
// Kernel 1: stable counting sort by expert id + compact 128-row job bands +
// work-queue counter init.
// ---------------------------------------------------------------------------
__global__ __launch_bounds__(256) void sort_experts(const int* __restrict__ idx,
                                                    int* __restrict__ perm,
                                                    int* __restrict__ offs,
                                                    int* __restrict__ jobs,
                                                    int* __restrict__ qcnt) {
  __shared__ int cnt[256][8];
  __shared__ int base[8];
  const int t = threadIdx.x;
  int local[8] = {0,0,0,0,0,0,0,0};
  const int r0 = t * 32;
  for (int i = 0; i < 32; ++i) {
    int e = idx[r0 + i] & 7;
    ++local[e];
  }
#pragma unroll
  for (int e = 0; e < 8; ++e) cnt[t][e] = local[e];
  __syncthreads();
  if (t < 8) {
    int s = 0;
    for (int i = 0; i < 256; ++i) { int v = cnt[i][t]; cnt[i][t] = s; s += v; }
    base[t] = s;
  }
  __syncthreads();
  if (t == 0) {
    int s = 0, njm = 0;
    for (int e = 0; e < 8; ++e) {
      int v = base[e];
      offs[e] = s; base[e] = s; s += v;
      int nm = (v + 127) >> 7;                     // 128-row bands
      for (int mt = 0; mt < nm; ++mt) jobs[1 + njm++] = e | (mt << 8);
    }
    offs[8] = s;
    jobs[0] = njm;
    qcnt[0] = 1024;                                // queue starts after grid
  }
  __syncthreads();
  int pos[8];
#pragma unroll
  for (int e = 0; e < 8; ++e) pos[e] = base[e] + cnt[t][e];
  for (int i = 0; i < 32; ++i) {
    int r = r0 + i;
    int e = idx[r] & 7;
    perm[pos[e]++] = r;
  }
}

// ---------------------------------------------------------------------------
// Kernel 2: merged prep. Blocks [0,8192): gather+convert x (sorted bf16).
// Blocks [8192,16384): W[e][d][h] fp32 -> Wt[e][h][d] bf16 (LDS transpose).
// ---------------------------------------------------------------------------
__global__ __launch_bounds__(256) void prep(const float* __restrict__ x,
                                            const int* __restrict__ perm,
                                            unsigned short* __restrict__ xs,
                                            const float* __restrict__ W,
                                            unsigned short* __restrict__ Wt) {
  __shared__ unsigned short tile[64][68];
  const int t = threadIdx.x;
  if (blockIdx.x < 8192) {
    int gid = blockIdx.x * 256 + t;
    int p = gid >> 8;
    int c = gid & 255;
    int src = perm[p];
    const float* sp = x + (size_t)src * DIM + c * 8;
    float4 a = *(const float4*)sp;
    float4 b = *(const float4*)(sp + 4);
    short8 o;
    o[0] = (short)f2bf(a.x); o[1] = (short)f2bf(a.y);
    o[2] = (short)f2bf(a.z); o[3] = (short)f2bf(a.w);
    o[4] = (short)f2bf(b.x); o[5] = (short)f2bf(b.y);
    o[6] = (short)f2bf(b.z); o[7] = (short)f2bf(b.w);
    *(short8*)(xs + (size_t)p * DIM + c * 8) = o;
  } else {
    const int b = blockIdx.x - 8192;
    const int e  = b >> 10;
    const int d0 = ((b >> 5) & 31) * 64;
    const int h0 = (b & 31) * 64;
    const int cr = t & 15;
    const int rr = t >> 4;
    const float* Wp = W + ((size_t)e * DIM + d0) * HID + h0;
#pragma unroll
    for (int i = 0; i < 4; ++i) {
      int d = rr + i * 16;
      float4 v = *(const float4*)(Wp + (size_t)d * HID + cr * 4);
      ushort4v o;
      o[0] = f2bf(v.x); o[1] = f2bf(v.y); o[2] = f2bf(v.z); o[3] = f2bf(v.w);
      *(ushort4v*)&tile[d][cr * 4] = o;
    }
    __syncthreads();
    unsigned short* op = Wt + ((size_t)e * HID + h0) * DIM + d0;
#pragma unroll
    for (int i = 0; i < 4; ++i) {
      int h = rr + i * 16;
      ushort4v o;
      o[0] = tile[cr * 4 + 0][h];
      o[1] = tile[cr * 4 + 1][h];
      o[2] = tile[cr * 4 + 2][h];
      o[3] = tile[cr * 4 + 3][h];
      *(ushort4v*)(op + (size_t)h * DIM + cr * 4) = o;
    }
  }
}

// ---------------------------------------------------------------------------
// Kernel 3: grouped GEMM, work-queue. 1024 blocks x 128 thr (2 waves).
// Job = 128(M) x 128(N) tile; per-wave 64x128 (acc 4x8). BK=64, single
// 32 KB LDS buffer -> 4 blocks/CU co-resident do the cross-block overlap.
// Block-uniform job steal (thread 0 atomicAdd + LDS broadcast).
// Swizzle (R3-verified): byte[6:4] ^= row[2:0] on reads, inverse
// pre-applied to global staging sources.
// ---------------------------------------------------------------------------
#define NKT 32   // K-tiles of 64

#define MM(D,A,B) D = __builtin_amdgcn_mfma_f32_16x16x32_bf16(A, B, D, 0, 0, 0)
#define GLD(SRC, DST) __builtin_amdgcn_global_load_lds( \
    (const __attribute__((address_space(1))) void*)(SRC), \
    (__attribute__((address_space(3))) void*)(DST), 16, 0, 0)
#define BAR() __builtin_amdgcn_s_barrier()
#define SCHEDB() __builtin_amdgcn_sched_barrier(0)

__global__ __launch_bounds__(128, 2) void grouped_gemm(
    const unsigned short* __restrict__ xs,
    const unsigned short* __restrict__ Wt,
    const float* __restrict__ bias,
    const int* __restrict__ offs,
    const int* __restrict__ jobs,
    int* __restrict__ qcnt,
    float* __restrict__ out) {
  __shared__ __align__(16) unsigned short sm[16384];   // A [0,8192) B [8192,16384)
  __shared__ int next_j;

  const int t    = threadIdx.x;
  const int lane = t & 63;
  const int w    = t >> 6;     // wave 0/1: C rows w*64..w*64+63
  const int l15  = lane & 15;
  const int l4   = lane >> 4;

  // Read-side swizzled fragment offsets (ushort units, 64-ush rows).
  const int cb0  = (l4 * 8) ^ ((l15 & 7) << 3);
  const int cb1  = cb0 ^ 32;
  const int arow = (w * 64 + l15) * 64;          // + m*1024, m 0..3
  const int brow = 8192 + l15 * 64;              // + n*1024, n 0..7

  // Staging: thread t covers row r0 = t>>3 of a 16-row chunk, 16B col t&7;
  // inverse swizzle pre-applied to global k index.
  const int r0  = t >> 3;
  const int keu = ((t & 7) * 8) ^ ((r0 & 7) << 3);
  const int dA  = t * 8;     // linear LDS dest (ushort) within a 2KB chunk

  const int total = jobs[0] * 16;

  int j = blockIdx.x;
  while (j < total) {
    const int jm  = jobs[1 + (j >> 4)];
    const int e   = jm & 255;
    const int mt  = jm >> 8;
    const int nx  = j & 15;
    const int off = offs[e];
    const int cnt = offs[e + 1] - off;
    const int n0  = nx * 128;
    const int aBase = off + mt * 128;

    // Source bases (element offsets at k=0). Unclamped A tail rows read a
    // few KB past xs into Wt (still inside ws) and are masked at store.
    const unsigned int pa = (unsigned)(aBase + r0) * 2048 + keu;
    const unsigned int pb = ((unsigned)e * 2048 + n0 + r0) * 2048 + keu;

    f32x4 acc[4][8];
#pragma unroll
    for (int m = 0; m < 4; ++m)
#pragma unroll
      for (int n = 0; n < 8; ++n) acc[m][n] = (f32x4){0.f, 0.f, 0.f, 0.f};

#pragma unroll 1
    for (int T = 0; T < NKT; ++T) {
      const int k0 = T * 64;
      // Stage tile T: A 8 chunks of 16 rows, B 8 chunks. 16 gload_lds.
#pragma unroll
      for (int ch = 0; ch < 8; ++ch)
        GLD(xs + pa + ch * 32768 + k0, sm + ch * 1024 + dA);
#pragma unroll
      for (int ch = 0; ch < 8; ++ch)
        GLD(Wt + pb + ch * 32768 + k0, sm + 8192 + ch * 1024 + dA);
      asm volatile("s_waitcnt vmcnt(0)" ::: "memory");
      BAR();
      SCHEDB();   // pin: no ds_read hoisted above the barrier

      short8 fa0, fa1, fa2, fa3;
      short8 fb0, fb1, fb2, fb3, fb4, fb5, fb6, fb7;
      // ---- ksub 0 ----
      fa0 = *(const short8*)(sm + arow + 0 * 1024 + cb0);
      fa1 = *(const short8*)(sm + arow + 1 * 1024 + cb0);
      fa2 = *(const short8*)(sm + arow + 2 * 1024 + cb0);
      fa3 = *(const short8*)(sm + arow + 3 * 1024 + cb0);
      fb0 = *(const short8*)(sm + brow + 0 * 1024 + cb0);
      fb1 = *(const short8*)(sm + brow + 1 * 1024 + cb0);
      fb2 = *(const short8*)(sm + brow + 2 * 1024 + cb0);
      fb3 = *(const short8*)(sm + brow + 3 * 1024 + cb0);
      fb4 = *(const short8*)(sm + brow + 4 * 1024 + cb0);
      fb5 = *(const short8*)(sm + brow + 5 * 1024 + cb0);
      fb6 = *(const short8*)(sm + brow + 6 * 1024 + cb0);
      fb7 = *(const short8*)(sm + brow + 7 * 1024 + cb0);
#pragma unroll
      for (int m = 0; m < 4; ++m) {
        const short8 fa = (m == 0) ? fa0 : (m == 1) ? fa1 : (m == 2) ? fa2 : fa3;
        MM(acc[m][0], fa, fb0); MM(acc[m][1], fa, fb1);
        MM(acc[m][2], fa, fb2); MM(acc[m][3], fa, fb3);
        MM(acc[m][4], fa, fb4); MM(acc[m][5], fa, fb5);
        MM(acc[m][6], fa, fb6); MM(acc[m][7], fa, fb7);
      }
      // ---- ksub 1 ----
      fa0 = *(const short8*)(sm + arow + 0 * 1024 + cb1);
      fa1 = *(const short8*)(sm + arow + 1 * 1024 + cb1);
      fa2 = *(const short8*)(sm + arow + 2 * 1024 + cb1);
      fa3 = *(const short8*)(sm + arow + 3 * 1024 + cb1);
      fb0 = *(const short8*)(sm + brow + 0 * 1024 + cb1);
      fb1 = *(const short8*)(sm + brow + 1 * 1024 + cb1);
      fb2 = *(const short8*)(sm + brow + 2 * 1024 + cb1);
      fb3 = *(const short8*)(sm + brow + 3 * 1024 + cb1);
      fb4 = *(const short8*)(sm + brow + 4 * 1024 + cb1);
      fb5 = *(const short8*)(sm + brow + 5 * 1024 + cb1);
      fb6 = *(const short8*)(sm + brow + 6 * 1024 + cb1);
      fb7 = *(const short8*)(sm + brow + 7 * 1024 + cb1);
#pragma unroll
      for (int m = 0; m < 4; ++m) {
        const short8 fa = (m == 0) ? fa0 : (m == 1) ? fa1 : (m == 2) ? fa2 : fa3;
        MM(acc[m][0], fa, fb0); MM(acc[m][1], fa, fb1);
        MM(acc[m][2], fa, fb2); MM(acc[m][3], fa, fb3);
        MM(acc[m][4], fa, fb4); MM(acc[m][5], fa, fb5);
        MM(acc[m][6], fa, fb6); MM(acc[m][7], fa, fb7);
      }
      BAR();      // all waves done reading; buffer free for tile T+1
      SCHEDB();   // pin: next tile's gload_lds stays below this barrier
    }

    // Epilogue: bias + relu, masked tail rows.
#pragma unroll
    for (int n = 0; n < 8; ++n) {
      int col = n0 + n * 16 + l15;
      float bv = bias[e * HID + col];
#pragma unroll
      for (int m = 0; m < 4; ++m) {
#pragma unroll
        for (int q = 0; q < 4; ++q) {
          int r = w * 64 + m * 16 + l4 * 4 + q;
          if (mt * 128 + r < cnt) {
            float v = acc[m][n][q] + bv;
            out[(size_t)(off + mt * 128 + r) * HID + col] = v > 0.f ? v : 0.f;
          }
        }
      }
    }

    // Block-uniform job steal: one atomic, broadcast, barrier both sides.
    __syncthreads();
    if (t == 0) next_j = atomicAdd(qcnt, 1);
    __syncthreads();
    j = next_j;
  }
}

// ---------------------------------------------------------------------------
extern "C" void kernel_launch(void* const* d_in, const int* in_sizes, int n_in,
                              void* d_out, int out_size, void* d_ws, size_t ws_size,
                              hipStream_t stream) {
  const float* x   = (const float*)d_in[0];
  const int*   idx = (const int*)d_in[1];
  const float* W   = (const float*)d_in[2];
  const float* b   = (const float*)d_in[3];
  float* out = (float*)d_out;

  char* ws = (char*)d_ws;
  unsigned short* xs = (unsigned short*)ws;                                   // 32 MB
  unsigned short* Wt = (unsigned short*)(ws + (size_t)N_TOK * DIM * 2);       // 64 MB
  int* perm = (int*)(ws + (size_t)N_TOK * DIM * 2 + (size_t)N_EXP * DIM * HID * 2);
  int* offs = perm + N_TOK;
  int* jobs = offs + 16;
  int* qcnt = jobs + 4096;

  sort_experts<<<1, 256, 0, stream>>>(idx, perm, offs, jobs, qcnt);
  prep<<<16384, 256, 0, stream>>>(x, perm, xs, W, Wt);
  grouped_gemm<<<1024, 128, 0, stream>>>(xs, Wt, b, offs, jobs, qcnt, out);
}